// Round 1
// baseline (105.696 us; speedup 1.0000x reference)
//
#include <hip/hip_runtime.h>
#include <hip/hip_bf16.h>

#define EMBED 768
#define HID 768
#define DTOT 1536
#define NASP 32
#define BATCHN 256
#define CH 8        // samples per chunk
#define MAXCHUNK 64 // sum ceil(n_a/8) <= 32 + 256/8 = 64
#define NTILE 6     // 768 / 128 column tiles

// meta layout (ints): [0]=n_chunks, [1..64]=chunk aspect, [65..128]=chunk cnt,
// [129..129+512)=chunk sample ids (8 per chunk)
#define META_ASPECT(c)  (1 + (c))
#define META_CNT(c)     (1 + MAXCHUNK + (c))
#define META_SMP(c, j)  (1 + 2 * MAXCHUNK + (c) * CH + (j))

__global__ __launch_bounds__(BATCHN) void bucket_kernel(
    const int* __restrict__ aspect_ids, int* __restrict__ meta)
{
    __shared__ int counts[NASP];
    __shared__ int chunkbase[NASP];
    int t = threadIdx.x;
    if (t < NASP) counts[t] = 0;
    __syncthreads();
    int a = aspect_ids[t];
    int r = atomicAdd(&counts[a], 1);
    __syncthreads();
    if (t == 0) {
        int c = 0;
        for (int i = 0; i < NASP; ++i) {
            chunkbase[i] = c;
            int n = counts[i];
            int nc = (n + CH - 1) / CH;
            for (int j = 0; j < nc; ++j) {
                meta[META_ASPECT(c + j)] = i;
                int rem = n - j * CH;
                meta[META_CNT(c + j)] = rem < CH ? rem : CH;
            }
            c += nc;
        }
        meta[0] = c;
    }
    __syncthreads();
    int c = chunkbase[a] + r / CH;
    meta[META_SMP(c, r % CH)] = t;
}

__global__ __launch_bounds__(256) void gemv1_kernel(
    const float* __restrict__ vX, const float* __restrict__ vH,
    const float* __restrict__ W1, const float* __restrict__ b1,
    const int* __restrict__ meta, float* __restrict__ out1)
{
    int nchunks = meta[0];
    int chunk = blockIdx.x / NTILE;
    int tile  = blockIdx.x % NTILE;
    if (chunk >= nchunks) return;

    int aspect = meta[META_ASPECT(chunk)];
    int cnt    = meta[META_CNT(chunk)];

    __shared__ int smp[CH];
    __shared__ float Vs[CH][128];

    int t = threadIdx.x;
    if (t < CH) {
        smp[t] = (t < cnt) ? meta[META_SMP(chunk, t)] : meta[META_SMP(chunk, 0)];
    }
    __syncthreads();

    int c32 = t & 31;     // which float4 of the 128-col tile
    int sg  = t >> 5;     // which sample of the chunk (0..7)
    int h   = tile * 128 + c32 * 4;
    int mysample = smp[sg];

    const float* Wbase = W1 + (size_t)aspect * ((size_t)DTOT * HID) + h;
    float acc0 = 0.f, acc1 = 0.f, acc2 = 0.f, acc3 = 0.f;

    for (int dc = 0; dc < DTOT / 128; ++dc) {
        int d0 = dc * 128;
        const float* vsrc = (d0 < EMBED)
            ? (vX + (size_t)mysample * EMBED + d0)
            : (vH + (size_t)mysample * HID + (d0 - EMBED));
        __syncthreads();
        // each thread stages its own sample-row's float4
        *(float4*)&Vs[sg][c32 * 4] = *(const float4*)(vsrc + c32 * 4);
        __syncthreads();

        const float* wp = Wbase + (size_t)d0 * HID;
        #pragma unroll 8
        for (int dd = 0; dd < 128; ++dd) {
            float4 w = *(const float4*)wp;
            wp += HID;
            float v = Vs[sg][dd];
            acc0 += v * w.x;
            acc1 += v * w.y;
            acc2 += v * w.z;
            acc3 += v * w.w;
        }
    }

    const float* b1p = b1 + (size_t)aspect * HID + h;
    acc0 = fmaxf(acc0 + b1p[0], 0.f);
    acc1 = fmaxf(acc1 + b1p[1], 0.f);
    acc2 = fmaxf(acc2 + b1p[2], 0.f);
    acc3 = fmaxf(acc3 + b1p[3], 0.f);

    if (sg < cnt) {
        float4 r;
        r.x = acc0; r.y = acc1; r.z = acc2; r.w = acc3;
        *(float4*)&out1[(size_t)mysample * HID + h] = r;
    }
}

__global__ __launch_bounds__(64) void head_kernel(
    const float* __restrict__ out1, const int* __restrict__ aspect_ids,
    const float* __restrict__ W2, const float* __restrict__ b2,
    float* __restrict__ logits)
{
    int s = blockIdx.x;
    int t = threadIdx.x;
    int a = aspect_ids[s];
    const float* o  = out1 + (size_t)s * HID;
    const float* w2 = W2 + (size_t)a * HID * 2;
    float p0 = 0.f, p1 = 0.f;
    #pragma unroll
    for (int j = 0; j < HID / 64; ++j) {
        int hh = t + j * 64;
        float ov = o[hh];
        p0 += ov * w2[hh * 2 + 0];
        p1 += ov * w2[hh * 2 + 1];
    }
    #pragma unroll
    for (int off = 32; off > 0; off >>= 1) {
        p0 += __shfl_down(p0, off, 64);
        p1 += __shfl_down(p1, off, 64);
    }
    if (t == 0) {
        logits[s * 2 + 0] = p0 + b2[a * 2 + 0];
        logits[s * 2 + 1] = p1 + b2[a * 2 + 1];
    }
}

extern "C" void kernel_launch(void* const* d_in, const int* in_sizes, int n_in,
                              void* d_out, int out_size, void* d_ws, size_t ws_size,
                              hipStream_t stream) {
    const float* vX  = (const float*)d_in[0];
    const float* vH  = (const float*)d_in[1];
    const int*   aid = (const int*)d_in[2];
    const float* W1  = (const float*)d_in[3];
    const float* b1  = (const float*)d_in[4];
    const float* W2  = (const float*)d_in[5];
    const float* b2  = (const float*)d_in[6];
    float* logits = (float*)d_out;

    int*   meta = (int*)d_ws;
    float* out1 = (float*)((char*)d_ws + 4096);

    bucket_kernel<<<1, BATCHN, 0, stream>>>(aid, meta);
    gemv1_kernel<<<MAXCHUNK * NTILE, 256, 0, stream>>>(vX, vH, W1, b1, meta, out1);
    head_kernel<<<BATCHN, 64, 0, stream>>>(out1, aid, W2, b2, logits);
}

// Round 2
// 43.258 us; speedup vs baseline: 2.4434x; 2.4434x over previous
//
#include <hip/hip_runtime.h>
#include <hip/hip_bf16.h>

#define EMBED 768
#define HID 768
#define DTOT 1536
#define NASP 32
#define BATCHN 256
#define CH 8        // samples per chunk
#define MAXCHUNK 64 // sum ceil(n_a/8) <= 32 + 256/8 = 64
#define NTILE 6     // 768 / 128 column tiles
#define DSPLIT 8    // 1536 / 192 row splits
#define DROWS (DTOT / DSPLIT)   // 192 rows per block

// meta layout (ints): [0]=n_chunks, [1..64]=chunk aspect, [65..128]=chunk cnt,
// [129..129+512)=chunk sample ids (8 per chunk)
#define META_ASPECT(c)  (1 + (c))
#define META_CNT(c)     (1 + MAXCHUNK + (c))
#define META_SMP(c, j)  (1 + 2 * MAXCHUNK + (c) * CH + (j))

__global__ __launch_bounds__(BATCHN) void bucket_kernel(
    const int* __restrict__ aspect_ids, int* __restrict__ meta)
{
    __shared__ int counts[NASP];
    __shared__ int chunkbase[NASP];
    int t = threadIdx.x;
    if (t < NASP) counts[t] = 0;
    __syncthreads();
    int a = aspect_ids[t];
    int r = atomicAdd(&counts[a], 1);
    __syncthreads();
    if (t == 0) {
        int c = 0;
        for (int i = 0; i < NASP; ++i) {
            chunkbase[i] = c;
            int n = counts[i];
            int nc = (n + CH - 1) / CH;
            for (int j = 0; j < nc; ++j) {
                meta[META_ASPECT(c + j)] = i;
                int rem = n - j * CH;
                meta[META_CNT(c + j)] = rem < CH ? rem : CH;
            }
            c += nc;
        }
        meta[0] = c;
    }
    __syncthreads();
    int c = chunkbase[a] + r / CH;
    meta[META_SMP(c, r % CH)] = t;
}

// Each block: one (chunk, 128-col tile, 192-row dsplit). Threads: c32 = t&31
// (col quad), dg = t>>5 (row offset 0..7). Every thread loads UNIQUE W data
// and accumulates all 8 samples from LDS-transposed V. Partials to `part`.
__global__ __launch_bounds__(256) void gemv1_kernel(
    const float* __restrict__ vX, const float* __restrict__ vH,
    const float* __restrict__ W1, const int* __restrict__ meta,
    float* __restrict__ part)
{
    int nchunks = meta[0];
    int bid = blockIdx.x;
    int chunk = bid / (NTILE * DSPLIT);
    if (chunk >= nchunks) return;
    int rem  = bid % (NTILE * DSPLIT);
    int tile = rem / DSPLIT;
    int dsp  = rem % DSPLIT;

    int aspect = meta[META_ASPECT(chunk)];
    int cnt    = meta[META_CNT(chunk)];

    __shared__ int smp[CH];
    __shared__ __align__(16) float Vs[DROWS][CH];   // 6 KB, transposed V
    __shared__ float4 red[256];                     // 4 KB reduce buffer

    int t = threadIdx.x;
    if (t < CH) {
        smp[t] = (t < cnt) ? meta[META_SMP(chunk, t)] : meta[META_SMP(chunk, 0)];
    }
    __syncthreads();

    int dbase = dsp * DROWS;
    // stage V[dbase..dbase+192) for 8 samples, transposed: Vs[d][s]
    for (int r = 0; r < 2; ++r) {
        int id = t + r * 256;
        if (id < CH * (DROWS / 4)) {      // 8 * 48 = 384 float4 loads
            int s = id / (DROWS / 4);
            int f = id % (DROWS / 4);
            int d = dbase + f * 4;
            const float* src = (dbase < EMBED)
                ? (vX + (size_t)smp[s] * EMBED + d)
                : (vH + (size_t)smp[s] * HID + (d - EMBED));
            float4 v = *(const float4*)src;
            Vs[f * 4 + 0][s] = v.x;
            Vs[f * 4 + 1][s] = v.y;
            Vs[f * 4 + 2][s] = v.z;
            Vs[f * 4 + 3][s] = v.w;
        }
    }
    __syncthreads();

    int c32 = t & 31;
    int dg  = t >> 5;
    int h   = tile * 128 + c32 * 4;

    const float* wp = W1 + (size_t)aspect * ((size_t)DTOT * HID)
                         + (size_t)(dbase + dg) * HID + h;

    float4 acc[CH];
    #pragma unroll
    for (int s = 0; s < CH; ++s) { acc[s].x = acc[s].y = acc[s].z = acc[s].w = 0.f; }

    #pragma unroll 4
    for (int k = 0; k < DROWS / 8; ++k) {   // 24 iterations
        float4 w = *(const float4*)wp;
        wp += 8 * HID;
        int d = k * 8 + dg;
        float4 vlo = *(const float4*)&Vs[d][0];
        float4 vhi = *(const float4*)&Vs[d][4];
        acc[0].x += vlo.x * w.x; acc[0].y += vlo.x * w.y; acc[0].z += vlo.x * w.z; acc[0].w += vlo.x * w.w;
        acc[1].x += vlo.y * w.x; acc[1].y += vlo.y * w.y; acc[1].z += vlo.y * w.z; acc[1].w += vlo.y * w.w;
        acc[2].x += vlo.z * w.x; acc[2].y += vlo.z * w.y; acc[2].z += vlo.z * w.z; acc[2].w += vlo.z * w.w;
        acc[3].x += vlo.w * w.x; acc[3].y += vlo.w * w.y; acc[3].z += vlo.w * w.z; acc[3].w += vlo.w * w.w;
        acc[4].x += vhi.x * w.x; acc[4].y += vhi.x * w.y; acc[4].z += vhi.x * w.z; acc[4].w += vhi.x * w.w;
        acc[5].x += vhi.y * w.x; acc[5].y += vhi.y * w.y; acc[5].z += vhi.y * w.z; acc[5].w += vhi.y * w.w;
        acc[6].x += vhi.z * w.x; acc[6].y += vhi.z * w.y; acc[6].z += vhi.z * w.z; acc[6].w += vhi.z * w.w;
        acc[7].x += vhi.w * w.x; acc[7].y += vhi.w * w.y; acc[7].z += vhi.w * w.z; acc[7].w += vhi.w * w.w;
    }

    // reduce over dg (8 thread groups) via LDS, one sample per round
    size_t dsp_off = (size_t)dsp * BATCHN * HID;
    for (int s = 0; s < CH; ++s) {
        __syncthreads();
        red[t] = acc[s];
        __syncthreads();
        if (t < 32) {
            float4 sum = red[t];
            #pragma unroll
            for (int g = 1; g < 8; ++g) {
                float4 o = red[g * 32 + t];
                sum.x += o.x; sum.y += o.y; sum.z += o.z; sum.w += o.w;
            }
            *(float4*)&part[dsp_off + (size_t)smp[s] * HID + tile * 128 + t * 4] = sum;
        }
    }
}

__global__ __launch_bounds__(64) void head_kernel(
    const float* __restrict__ part, const int* __restrict__ aspect_ids,
    const float* __restrict__ b1, const float* __restrict__ W2,
    const float* __restrict__ b2, float* __restrict__ logits)
{
    int s = blockIdx.x;
    int t = threadIdx.x;
    int a = aspect_ids[s];
    const float* w2 = W2 + (size_t)a * HID * 2;
    const float* b1p = b1 + (size_t)a * HID;
    float p0 = 0.f, p1 = 0.f;
    #pragma unroll
    for (int j = 0; j < HID / 64; ++j) {
        int hh = t + j * 64;
        float o = 0.f;
        #pragma unroll
        for (int p = 0; p < DSPLIT; ++p) {
            o += part[(size_t)p * BATCHN * HID + (size_t)s * HID + hh];
        }
        o = fmaxf(o + b1p[hh], 0.f);
        p0 += o * w2[hh * 2 + 0];
        p1 += o * w2[hh * 2 + 1];
    }
    #pragma unroll
    for (int off = 32; off > 0; off >>= 1) {
        p0 += __shfl_down(p0, off, 64);
        p1 += __shfl_down(p1, off, 64);
    }
    if (t == 0) {
        logits[s * 2 + 0] = p0 + b2[a * 2 + 0];
        logits[s * 2 + 1] = p1 + b2[a * 2 + 1];
    }
}

extern "C" void kernel_launch(void* const* d_in, const int* in_sizes, int n_in,
                              void* d_out, int out_size, void* d_ws, size_t ws_size,
                              hipStream_t stream) {
    const float* vX  = (const float*)d_in[0];
    const float* vH  = (const float*)d_in[1];
    const int*   aid = (const int*)d_in[2];
    const float* W1  = (const float*)d_in[3];
    const float* b1  = (const float*)d_in[4];
    const float* W2  = (const float*)d_in[5];
    const float* b2  = (const float*)d_in[6];
    float* logits = (float*)d_out;

    int*   meta = (int*)d_ws;
    float* part = (float*)((char*)d_ws + 4096);   // 8*256*768*4 = 6.29 MB

    bucket_kernel<<<1, BATCHN, 0, stream>>>(aid, meta);
    gemv1_kernel<<<MAXCHUNK * NTILE * DSPLIT, 256, 0, stream>>>(vX, vH, W1, meta, part);
    head_kernel<<<BATCHN, 64, 0, stream>>>(part, aid, b1, W2, b2, logits);
}

// Round 3
// 40.087 us; speedup vs baseline: 2.6367x; 1.0791x over previous
//
#include <hip/hip_runtime.h>
#include <hip/hip_bf16.h>

#define EMBED 768
#define HID 768
#define DTOT 1536
#define NASP 32
#define BATCHN 256
#define CH 16        // samples per chunk (>= typical max n_a -> ~no duplication)
#define MAXCHUNK 48  // 32 + 256/16
#define NTILE 6      // 768 / 128 column tiles
#define DSPLIT 8     // 1536 / 192 row splits
#define DROWS (DTOT / DSPLIT)   // 192 rows per block

// Each block: one (chunk, 128-col tile, 192-row dsplit).
// Bucketing (sample -> chunk) is recomputed per block DETERMINISTICALLY via
// ballot-ranking (no atomics), so all blocks agree on the mapping.
__global__ __launch_bounds__(256, 4) void gemv1_kernel(
    const float* __restrict__ vX, const float* __restrict__ vH,
    const float* __restrict__ W1, const int* __restrict__ aspect_ids,
    float* __restrict__ part)
{
    __shared__ int wcnt[4][NASP];          // per-wave aspect counts
    __shared__ int basearr[NASP];          // chunk base per aspect
    __shared__ int countsarr[NASP];        // total count per aspect
    __shared__ int chasp[MAXCHUNK];        // chunk -> aspect
    __shared__ int smpall[MAXCHUNK][CH];   // chunk -> sample ids
    __shared__ int nchunks_s;
    __shared__ __align__(16) float Vs[DROWS][CH];  // 12 KB transposed V
    __shared__ __align__(16) float4 red[512];      // 8 KB reduce buffer

    int t = threadIdx.x;
    int lane = t & 63;
    int wave = t >> 6;
    int myaid = aspect_ids[t];

    // --- deterministic bucketing ---
    unsigned long long mymask = 0ull;
    for (int a = 0; a < NASP; ++a) {
        bool p = (myaid == a);
        unsigned long long m = __ballot(p);
        if (p) mymask = m;
        if (lane == a) wcnt[wave][a] = __popcll(m);
    }
    __syncthreads();
    if (t < NASP) {
        int ctot = wcnt[0][t] + wcnt[1][t] + wcnt[2][t] + wcnt[3][t];
        countsarr[t] = ctot;
        int nc = (ctot + CH - 1) / CH;
        // inclusive scan of nc over lanes 0..31 (all in wave 0)
        int incl = nc;
        #pragma unroll
        for (int off = 1; off < NASP; off <<= 1) {
            int v = __shfl_up(incl, off, 64);
            if (t >= off) incl += v;
        }
        int base = incl - nc;
        basearr[t] = base;
        for (int j = 0; j < nc; ++j) chasp[base + j] = t;
        if (t == NASP - 1) nchunks_s = incl;
    }
    __syncthreads();
    {
        int pre = 0;
        for (int w2 = 0; w2 < wave; ++w2) pre += wcnt[w2][myaid];
        int r = pre + __popcll(mymask & ((1ull << lane) - 1ull));
        int c = basearr[myaid] + r / CH;
        smpall[c][r % CH] = t;
    }
    __syncthreads();

    int bid = blockIdx.x;
    int chunk = bid / (NTILE * DSPLIT);
    if (chunk >= nchunks_s) return;
    int rem  = bid % (NTILE * DSPLIT);
    int tile = rem / DSPLIT;
    int dsp  = rem % DSPLIT;

    int aspect = chasp[chunk];
    int cnt = countsarr[aspect] - CH * (chunk - basearr[aspect]);
    if (cnt > CH) cnt = CH;

    int dbase = dsp * DROWS;

    // --- stage V transposed: Vs[d][s], s-fastest lanes (4-way store conflict max)
    #pragma unroll
    for (int r = 0; r < 3; ++r) {
        int id = t + r * 256;   // < 768 = 48 quads * 16 samples
        int s = id & (CH - 1);
        int f = id >> 4;        // 0..47 row-quad
        int smp = (s < cnt) ? smpall[chunk][s] : smpall[chunk][0];
        int d = dbase + f * 4;
        const float* src = (dbase < EMBED)
            ? (vX + (size_t)smp * EMBED + d)
            : (vH + (size_t)smp * HID + (d - EMBED));
        float4 v = *(const float4*)src;
        Vs[f * 4 + 0][s] = v.x;
        Vs[f * 4 + 1][s] = v.y;
        Vs[f * 4 + 2][s] = v.z;
        Vs[f * 4 + 3][s] = v.w;
    }
    __syncthreads();

    int c32 = t & 31;
    int dg  = t >> 5;
    int h   = tile * 128 + c32 * 4;

    const float* wp = W1 + (size_t)aspect * ((size_t)DTOT * HID)
                         + (size_t)(dbase + dg) * HID + h;

    float4 acc[CH];
    #pragma unroll
    for (int s = 0; s < CH; ++s) { acc[s].x = acc[s].y = acc[s].z = acc[s].w = 0.f; }

    #pragma unroll 4
    for (int k = 0; k < DROWS / 8; ++k) {   // 24 iterations
        float4 w = *(const float4*)wp;
        wp += 8 * HID;
        int d = k * 8 + dg;
        float4 va = *(const float4*)&Vs[d][0];
        float4 vb = *(const float4*)&Vs[d][4];
        float4 vc = *(const float4*)&Vs[d][8];
        float4 vd = *(const float4*)&Vs[d][12];
        acc[0].x  += va.x * w.x; acc[0].y  += va.x * w.y; acc[0].z  += va.x * w.z; acc[0].w  += va.x * w.w;
        acc[1].x  += va.y * w.x; acc[1].y  += va.y * w.y; acc[1].z  += va.y * w.z; acc[1].w  += va.y * w.w;
        acc[2].x  += va.z * w.x; acc[2].y  += va.z * w.y; acc[2].z  += va.z * w.z; acc[2].w  += va.z * w.w;
        acc[3].x  += va.w * w.x; acc[3].y  += va.w * w.y; acc[3].z  += va.w * w.z; acc[3].w  += va.w * w.w;
        acc[4].x  += vb.x * w.x; acc[4].y  += vb.x * w.y; acc[4].z  += vb.x * w.z; acc[4].w  += vb.x * w.w;
        acc[5].x  += vb.y * w.x; acc[5].y  += vb.y * w.y; acc[5].z  += vb.y * w.z; acc[5].w  += vb.y * w.w;
        acc[6].x  += vb.z * w.x; acc[6].y  += vb.z * w.y; acc[6].z  += vb.z * w.z; acc[6].w  += vb.z * w.w;
        acc[7].x  += vb.w * w.x; acc[7].y  += vb.w * w.y; acc[7].z  += vb.w * w.z; acc[7].w  += vb.w * w.w;
        acc[8].x  += vc.x * w.x; acc[8].y  += vc.x * w.y; acc[8].z  += vc.x * w.z; acc[8].w  += vc.x * w.w;
        acc[9].x  += vc.y * w.x; acc[9].y  += vc.y * w.y; acc[9].z  += vc.y * w.z; acc[9].w  += vc.y * w.w;
        acc[10].x += vc.z * w.x; acc[10].y += vc.z * w.y; acc[10].z += vc.z * w.z; acc[10].w += vc.z * w.w;
        acc[11].x += vc.w * w.x; acc[11].y += vc.w * w.y; acc[11].z += vc.w * w.z; acc[11].w += vc.w * w.w;
        acc[12].x += vd.x * w.x; acc[12].y += vd.x * w.y; acc[12].z += vd.x * w.z; acc[12].w += vd.x * w.w;
        acc[13].x += vd.y * w.x; acc[13].y += vd.y * w.y; acc[13].z += vd.y * w.z; acc[13].w += vd.y * w.w;
        acc[14].x += vd.z * w.x; acc[14].y += vd.z * w.y; acc[14].z += vd.z * w.z; acc[14].w += vd.z * w.w;
        acc[15].x += vd.w * w.x; acc[15].y += vd.w * w.y; acc[15].z += vd.w * w.z; acc[15].w += vd.w * w.w;
    }

    // --- reduce over dg (8 groups) via LDS, 2 samples per round ---
    size_t dsp_off = (size_t)dsp * BATCHN * HID;
    #pragma unroll
    for (int sp = 0; sp < CH / 2; ++sp) {
        __syncthreads();
        red[t]       = acc[2 * sp + 0];
        red[256 + t] = acc[2 * sp + 1];
        __syncthreads();
        if (t < 64) {
            int half = t >> 5;          // which of the 2 samples
            int l32  = t & 31;
            int s = 2 * sp + half;
            float4 sum = red[half * 256 + l32];
            #pragma unroll
            for (int g = 1; g < 8; ++g) {
                float4 o = red[half * 256 + g * 32 + l32];
                sum.x += o.x; sum.y += o.y; sum.z += o.z; sum.w += o.w;
            }
            if (s < cnt) {
                int smp = smpall[chunk][s];
                *(float4*)&part[dsp_off + (size_t)smp * HID + tile * 128 + l32 * 4] = sum;
            }
        }
    }
}

__global__ __launch_bounds__(64) void head_kernel(
    const float* __restrict__ part, const int* __restrict__ aspect_ids,
    const float* __restrict__ b1, const float* __restrict__ W2,
    const float* __restrict__ b2, float* __restrict__ logits)
{
    int s = blockIdx.x;
    int t = threadIdx.x;
    int a = aspect_ids[s];
    const float* w2 = W2 + (size_t)a * HID * 2;
    const float* b1p = b1 + (size_t)a * HID;
    float p0 = 0.f, p1 = 0.f;
    #pragma unroll
    for (int j = 0; j < HID / 64; ++j) {
        int hh = t + j * 64;
        float o = 0.f;
        #pragma unroll
        for (int p = 0; p < DSPLIT; ++p) {
            o += part[(size_t)p * BATCHN * HID + (size_t)s * HID + hh];
        }
        o = fmaxf(o + b1p[hh], 0.f);
        p0 += o * w2[hh * 2 + 0];
        p1 += o * w2[hh * 2 + 1];
    }
    #pragma unroll
    for (int off = 32; off > 0; off >>= 1) {
        p0 += __shfl_down(p0, off, 64);
        p1 += __shfl_down(p1, off, 64);
    }
    if (t == 0) {
        logits[s * 2 + 0] = p0 + b2[a * 2 + 0];
        logits[s * 2 + 1] = p1 + b2[a * 2 + 1];
    }
}

extern "C" void kernel_launch(void* const* d_in, const int* in_sizes, int n_in,
                              void* d_out, int out_size, void* d_ws, size_t ws_size,
                              hipStream_t stream) {
    const float* vX  = (const float*)d_in[0];
    const float* vH  = (const float*)d_in[1];
    const int*   aid = (const int*)d_in[2];
    const float* W1  = (const float*)d_in[3];
    const float* b1  = (const float*)d_in[4];
    const float* W2  = (const float*)d_in[5];
    const float* b2  = (const float*)d_in[6];
    float* logits = (float*)d_out;

    float* part = (float*)d_ws;   // 8*256*768*4 = 6.29 MB

    gemv1_kernel<<<MAXCHUNK * NTILE * DSPLIT, 256, 0, stream>>>(vX, vH, W1, aid, part);
    head_kernel<<<BATCHN, 64, 0, stream>>>(part, aid, b1, W2, b2, logits);
}